// Round 15
// baseline (93.636 us; speedup 1.0000x reference)
//
#include <hip/hip_runtime.h>
#include <hip/hip_bf16.h>

// B=16, N=2048, DIM_X=512, DIM_E=64, F=576 (=512+64)
// out_b = Xe_b * (Wbig * (Xe_b^T x_b))  -- three NT-GEMMs, no NxN matrix.
// Round-14 champion (88.1us) + Xb eliminated: g3 reg-stages A directly from
// x (f32 -> bf16 hw cvt -> ds_write, same lane->slot layout as gload_lds);
// convert's x-path now writes only XT.

typedef __attribute__((ext_vector_type(8))) short s16x8;
typedef __attribute__((ext_vector_type(4))) short s16x4;
typedef __attribute__((ext_vector_type(4))) float f32x4;

__device__ __forceinline__ unsigned short f2bf(float f) {
  union { float f; unsigned u; } v; v.f = f;
  unsigned r = v.u + 0x7fff + ((v.u >> 16) & 1);   // RNE
  return (unsigned short)(r >> 16);
}

__device__ __forceinline__ unsigned short hwbf(float f) {
  return __bfloat16_as_ushort(__float2bfloat16(f));  // HW RNE cvt (cvt_pk)
}

// ---------------------------------------------------------------------------
// NT-GEMM: C[i][j] = sum_k A[i][k]*B[j][k]. A: MxK, B: NxK row-major bf16;
// C: MxN (bf16 or f32). TMxTN tile, TK=64, 256 threads = 4 waves (2x2).
// global_load_lds w16 staging, 2-buffer LDS, prefetch-before-compute, ONE
// __syncthreads per K-tile (counted-vmcnt REGRESSED -- round 5; split-K
// REGRESSED -- round 13). LDS swizzle both-sides (16B slot ^= row&7) via
// pre-swizzled global source. XCD batch grouping. Integer blocks/CU grids.
// KSW>=0: A-source for k-tiles t>=KSW switches to batch-shared A2 (lda2).
// BSW:   B-source for rows >=512 switches to batch-shared B2 (same ldb).
// REGA:  A-source for t<KSW is f32 Af (lda f32 elems): reg-staged with HW
//        bf16 cvt into the SAME LDS layout gload_lds produces.
// ---------------------------------------------------------------------------
template<int TM, int TN, int GX, int GY, int OUT_F32, int KSW, int BSW, int REGA>
__global__ __launch_bounds__(256) void gemm_nt(
    const unsigned short* __restrict__ A, const float* __restrict__ Af,
    long sAb, int lda,
    const unsigned short* __restrict__ A2, int lda2,
    const unsigned short* __restrict__ B, const unsigned short* __restrict__ B2,
    long sBb, int ldb,
    void* __restrict__ Cptr, long sCb, int ldc,
    int K)
{
  constexpr int TK = 64;
  constexpr int WM = TM / 2, WN = TN / 2;
  constexpr int AM = WM / 16, AN = WN / 16;
  constexpr int ACH = TM / 8;
  constexpr int BCH = TN / 8;
  constexpr int NBLK = GX * GY;

  __shared__ unsigned short As[2][TM * TK];
  __shared__ unsigned short Bs[2][TN * TK];

  const int bid  = blockIdx.x;
  const int xcd  = bid & 7;
  const int slot = bid >> 3;
  const int bz   = xcd + 8 * (slot / NBLK);
  const int tix  = slot % NBLK;
  const int m0   = (tix % GX) * TM;
  const int n0   = (tix / GX) * TN;

  const unsigned short* Ab = REGA ? nullptr : (A + (long)bz * sAb);
  const float*          Afb = REGA ? (Af + (long)bz * sAb) : nullptr;
  const unsigned short* Bb = B + (long)bz * sBb;

  const int tid  = threadIdx.x;
  const int lane = tid & 63;
  const int wave = tid >> 6;
  const int wm = (wave >> 1) * WM;
  const int wn = (wave & 1) * WN;
  const int fr = lane & 15;
  const int fg = lane >> 4;
  const int fx = fr & 7;

  const int srow = lane >> 3;
  const int scol = (((lane & 7) ^ (lane >> 3)) & 7) * 8;  // pre-swizzled src col

  f32x4 acc[AM][AN];
#pragma unroll
  for (int i = 0; i < AM; i++)
#pragma unroll
    for (int j = 0; j < AN; j++) acc[i][j] = (f32x4)(0.f);

  auto stage = [&](int buf, int t) {
    const int k0 = t * TK;
    if (REGA && (KSW < 0 || t < KSW)) {
      // reg-staged A from f32: 2x float4 load -> 8 bf16 (HW cvt) -> b128 write
#pragma unroll
      for (int i = 0; i < ACH / 4; i++) {
        const int c = wave * (ACH / 4) + i;
        const float* src = Afb + (long)(m0 + c * 8 + srow) * lda + k0 + scol;
        const float4 a = *(const float4*)src;
        const float4 b = *(const float4*)(src + 4);
        s16x8 o;
        o[0] = hwbf(a.x); o[1] = hwbf(a.y); o[2] = hwbf(a.z); o[3] = hwbf(a.w);
        o[4] = hwbf(b.x); o[5] = hwbf(b.y); o[6] = hwbf(b.z); o[7] = hwbf(b.w);
        *(s16x8*)&As[buf][c * 512 + lane * 8] = o;
      }
    } else {
      const unsigned short* asrc;
      int asl;
      if (KSW >= 0 && t >= KSW) { asrc = A2 + (k0 - KSW * TK); asl = lda2; }
      else                      { asrc = Ab + k0;              asl = lda;  }
#pragma unroll
      for (int i = 0; i < ACH / 4; i++) {
        const int c = wave * (ACH / 4) + i;
        __builtin_amdgcn_global_load_lds(
            (const __attribute__((address_space(1))) unsigned*)
                (asrc + (long)(m0 + c * 8 + srow) * asl + scol),
            (__attribute__((address_space(3))) unsigned*)(&As[buf][c * 512]),
            16, 0, 0);
      }
    }
#pragma unroll
    for (int i = 0; i < BCH / 4; i++) {
      const int c = wave * (BCH / 4) + i;
      const int br = n0 + c * 8;      // chunk rows [br, br+8): one side of 512
      const unsigned short* bsrc = (BSW && br >= 512)
          ? B2 + (long)(br - 512) * ldb
          : Bb + (long)br * ldb;
      __builtin_amdgcn_global_load_lds(
          (const __attribute__((address_space(1))) unsigned*)
              (bsrc + (long)srow * ldb + k0 + scol),
          (__attribute__((address_space(3))) unsigned*)(&Bs[buf][c * 512]),
          16, 0, 0);
    }
  };

  const int NT = K / TK;
  stage(0, 0);
  __syncthreads();

  for (int t = 0; t < NT; ++t) {
    const int cur = t & 1;
    if (t + 1 < NT) stage(cur ^ 1, t + 1);

    const unsigned short* Ac = &As[cur][0];
    const unsigned short* Bc = &Bs[cur][0];
#pragma unroll
    for (int ks = 0; ks < 2; ks++) {
      s16x8 av[AM], bv[AN];
#pragma unroll
      for (int mt = 0; mt < AM; mt++)
        av[mt] = *(const s16x8*)
            &Ac[(wm + mt * 16 + fr) * TK + (((ks * 4 + fg) ^ fx) * 8)];
#pragma unroll
      for (int nt = 0; nt < AN; nt++)
        bv[nt] = *(const s16x8*)
            &Bc[(wn + nt * 16 + fr) * TK + (((ks * 4 + fg) ^ fx) * 8)];
#pragma unroll
      for (int mt = 0; mt < AM; mt++)
#pragma unroll
        for (int nt = 0; nt < AN; nt++)
          acc[mt][nt] = __builtin_amdgcn_mfma_f32_16x16x32_bf16(
              av[mt], bv[nt], acc[mt][nt], 0, 0, 0);
    }
    __syncthreads();
  }

  // D layout (verified m89): col = lane&15, row = (lane>>4)*4 + j
  if (OUT_F32) {
    float* C = (float*)Cptr + (long)bz * sCb;
#pragma unroll
    for (int mt = 0; mt < AM; mt++) {
      const int row = m0 + wm + mt * 16 + fg * 4;
#pragma unroll
      for (int nt = 0; nt < AN; nt++) {
        const int col = n0 + wn + nt * 16 + fr;
#pragma unroll
        for (int j = 0; j < 4; j++)
          C[(long)(row + j) * ldc + col] = acc[mt][nt][j];
      }
    }
  } else {
    unsigned short* C = (unsigned short*)Cptr + (long)bz * sCb;
#pragma unroll
    for (int mt = 0; mt < AM; mt++) {
      const int row = m0 + wm + mt * 16 + fg * 4;
#pragma unroll
      for (int nt = 0; nt < AN; nt++) {
        const int col = n0 + wn + nt * 16 + fr;
#pragma unroll
        for (int j = 0; j < 4; j++)
          C[(long)(row + j) * ldc + col] = f2bf(acc[mt][nt][j]);
      }
    }
  }
}

// ---------------------------------------------------------------------------
// convert_fused (+Wb): round-12 LDS scheme (scalar transposed writes,
// vectorized b128 reads). Xb removed (g3 reads x directly now).
// z<16, y<8:  x 64x64 tile -> XT (transposed, per-batch). No straight copy.
// z==0, y==8: e 64x64 tile -> eb (straight) + eT (transposed) ONCE.
// z>0,  y==8: early exit.
// z in {16,17}: Wb[m][k] = quadrant transpose of W0..W3, relu(striu) on W0.
// ---------------------------------------------------------------------------
__global__ __launch_bounds__(256) void convert_fused(
    const float* __restrict__ x, const float* __restrict__ e,
    const float* __restrict__ W0, const float* __restrict__ W1,
    const float* __restrict__ W2, const float* __restrict__ W3,
    unsigned short* __restrict__ XT, unsigned short* __restrict__ eT,
    unsigned short* __restrict__ eb, unsigned short* __restrict__ Wb)
{
  constexpr int KP = 66;             // k stride in elems (64 + 2 pad)
  __shared__ unsigned short t[64 * KP];   // [f][k], 8448B; Wb path reuses 4224B

  if (blockIdx.z >= 16) {
    const int tidx = (blockIdx.z - 16) * 288 + blockIdx.y * 32 + blockIdx.x;
    if (tidx >= 324) return;
    float* tw = (float*)t;                  // [32][33]
    const int m0 = (tidx / 18) * 32;
    const int k0 = (tidx % 18) * 32;
    const int r  = threadIdx.x >> 3;        // 0..31
    const int c4 = (threadIdx.x & 7) * 4;   // 0..28

    const int k = k0 + r;
    float4 v;
    if (m0 < 512) {
      if (k0 < 512) v = *(const float4*)&W0[k * 512 + m0 + c4];
      else          v = *(const float4*)&W1[(k - 512) * 512 + m0 + c4];
    } else {
      if (k0 < 512) v = *(const float4*)&W2[k * 64 + (m0 - 512) + c4];
      else          v = *(const float4*)&W3[(k - 512) * 64 + (m0 - 512) + c4];
    }
    tw[r * 33 + c4 + 0] = v.x; tw[r * 33 + c4 + 1] = v.y;
    tw[r * 33 + c4 + 2] = v.z; tw[r * 33 + c4 + 3] = v.w;
    __syncthreads();

    const int m = m0 + r;
    const bool tri = (m0 < 512) && (k0 < 512);
    s16x4 o;
#pragma unroll
    for (int j = 0; j < 4; ++j) {
      const int kk = k0 + c4 + j;
      float val = tw[(c4 + j) * 33 + r];
      if (tri) val = (m > kk) ? fmaxf(val, 0.f) : 0.f;
      o[j] = f2bf(val);
    }
    *(s16x4*)&Wb[m * 576 + k0 + c4] = o;
    return;
  }

  const int b  = blockIdx.z;
  const int k0 = blockIdx.x * 64;
  const bool isE = (blockIdx.y == 8);
  if (isE && b != 0) return;              // e-block is batch-shared
  const int f0 = blockIdx.y * 64;
  const int l  = threadIdx.x & 63;
  const int w  = threadIdx.x >> 6;
  const int fi = (l & 15) * 4;

#pragma unroll
  for (int it = 0; it < 4; ++it) {
    const int row = w * 16 + it * 4 + (l >> 4);   // k within tile
    const int k = k0 + row;
    float4 v = isE ? *(const float4*)&e[(long)k * 64 + fi]
                   : *(const float4*)&x[((long)b * 2048 + k) * 512 + f0 + fi];
    s16x4 o; o[0] = f2bf(v.x); o[1] = f2bf(v.y); o[2] = f2bf(v.z); o[3] = f2bf(v.w);
    if (isE) *(s16x4*)&eb[(long)k * 64 + fi] = o;
    t[(fi + 0) * KP + row] = o[0];
    t[(fi + 1) * KP + row] = o[1];
    t[(fi + 2) * KP + row] = o[2];
    t[(fi + 3) * KP + row] = o[3];
  }
  __syncthreads();

  const int fr = threadIdx.x >> 2;        // 0..63
  const int kq = (threadIdx.x & 3) * 8;   // 0,8,16,24
  const s16x8 o0 = *(const s16x8*)&t[fr * KP + kq];
  const s16x8 o1 = *(const s16x8*)&t[fr * KP + kq + 32];
  const long obase = isE ? ((long)fr * 2048 + k0)
                         : (((long)b * 512 + f0 + fr) * 2048 + k0);
  unsigned short* dst = isE ? eT : XT;
  *(s16x8*)&dst[obase + kq]      = o0;
  *(s16x8*)&dst[obase + kq + 32] = o1;
}

// ---------------------------------------------------------------------------
extern "C" void kernel_launch(void* const* d_in, const int* in_sizes, int n_in,
                              void* d_out, int out_size, void* d_ws, size_t ws_size,
                              hipStream_t stream) {
  const float* x  = (const float*)d_in[0];
  const float* e  = (const float*)d_in[1];
  const float* W0 = (const float*)d_in[2];
  const float* W1 = (const float*)d_in[3];
  const float* W2 = (const float*)d_in[4];
  const float* W3 = (const float*)d_in[5];
  float* out = (float*)d_out;

  const size_t SZ_XT  = (size_t)16 * 512 * 2048 * 2;  // 33,554,432
  const size_t SZ_ET  = (size_t)64 * 2048 * 2;        //    262,144
  const size_t SZ_CT  = (size_t)16 * 512 * 576 * 2;   //  9,437,184
  const size_t SZ_DT  = SZ_CT;
  const size_t SZ_WB  = (size_t)576 * 576 * 2;        //    663,552
  const size_t SZ_EB  = (size_t)2048 * 64 * 2;        //    262,144

  char* p = (char*)d_ws;
  unsigned short* XT = (unsigned short*)p;  p += SZ_XT;
  unsigned short* eT = (unsigned short*)p;  p += SZ_ET;
  unsigned short* CT = (unsigned short*)p;  p += SZ_CT;
  unsigned short* DT = (unsigned short*)p;  p += SZ_DT;
  unsigned short* Wb = (unsigned short*)p;  p += SZ_WB;
  unsigned short* eb = (unsigned short*)p;  p += SZ_EB;
  const size_t base = SZ_XT + SZ_ET + SZ_CT + SZ_DT + SZ_WB + SZ_EB;
  if (ws_size < base) return;  // d_ws is 256MiB; loud failure otherwise

  // Fused pre-pass: x -> XT, e -> eb+eT (once), W0..W3 -> Wb
  convert_fused<<<dim3(32, 9, 18), 256, 0, stream>>>(
      x, e, W0, W1, W2, W3, XT, eT, eb, Wb);

  // Stage 1: CT[i][j] = sum_k XT[i][k] * {XT|eT}[j][k]  (M=512,N=576,K=2048)
  gemm_nt<64, 96, 8, 6, 0, -1, 1, 0><<<768, 256, 0, stream>>>(
      XT, nullptr, (long)512 * 2048, 2048, nullptr, 0,
      XT, eT, (long)512 * 2048, 2048,
      CT, (long)512 * 576, 576, 2048);

  // Stage 2: DT[t][m] = sum_f CT[t][f]*Wb[m][f]     (M=512, N=576, K=576)
  gemm_nt<64, 96, 8, 6, 0, -1, 0, 0><<<768, 256, 0, stream>>>(
      CT, nullptr, (long)512 * 576, 576, nullptr, 0,
      Wb, nullptr, 0L, 576,
      DT, (long)512 * 576, 576, 576);

  // Stage 3: out[n][t] = sum_m A[n][m]*DT[t][m]     (M=2048, N=512, K=576)
  // A: k-tiles 0..7 reg-staged from x (f32 -> bf16 HW cvt), tile 8 from eb.
  gemm_nt<128, 128, 16, 4, 1, 8, 0, 1><<<1024, 256, 0, stream>>>(
      nullptr, x, (long)2048 * 512, 512, eb, 64,
      DT, nullptr, (long)512 * 576, 576,
      out, (long)2048 * 512, 512, 576);
}

// Round 16
// 88.092 us; speedup vs baseline: 1.0629x; 1.0629x over previous
//
#include <hip/hip_runtime.h>
#include <hip/hip_bf16.h>

// B=16, N=2048, DIM_X=512, DIM_E=64, F=576 (=512+64)
// out_b = Xe_b * (Wbig * (Xe_b^T x_b))  -- three NT-GEMMs, no NxN matrix.
// EXACT revert to round-14 champion (88.09us). Round-15's reg-staged-A
// REGRESSED g3 19.5->42.8us (VGPR 88, occupancy 17%, doubled A-bytes,
// synchronous staging vs gload_lds DMA). Do not replace gload_lds with
// reg-staging on hot GEMM operands (also round 13).

typedef __attribute__((ext_vector_type(8))) short s16x8;
typedef __attribute__((ext_vector_type(4))) short s16x4;
typedef __attribute__((ext_vector_type(4))) float f32x4;

__device__ __forceinline__ unsigned short f2bf(float f) {
  union { float f; unsigned u; } v; v.f = f;
  unsigned r = v.u + 0x7fff + ((v.u >> 16) & 1);   // RNE
  return (unsigned short)(r >> 16);
}

// ---------------------------------------------------------------------------
// NT-GEMM: C[i][j] = sum_k A[i][k]*B[j][k]. A: MxK, B: NxK row-major bf16;
// C: MxN (bf16 or f32). TMxTN tile, TK=64, 256 threads = 4 waves (2x2).
// global_load_lds w16 staging, 2-buffer LDS, prefetch-before-compute, ONE
// __syncthreads per K-tile (counted-vmcnt REGRESSED -- round 5; split-K
// REGRESSED -- round 13; reg-staged A REGRESSED -- rounds 13/15). LDS
// swizzle both-sides (16B slot ^= row&7) via pre-swizzled global source.
// XCD batch grouping. Integer blocks/CU grids (rounds 6/8).
// KSW>=0: A-source for k-tiles t>=KSW switches to batch-shared A2 (lda2).
// BSW:   B-source for rows >=512 switches to batch-shared B2 (same ldb).
// ---------------------------------------------------------------------------
template<int TM, int TN, int GX, int GY, int OUT_F32, int KSW, int BSW>
__global__ __launch_bounds__(256) void gemm_nt(
    const unsigned short* __restrict__ A, long sAb, int lda,
    const unsigned short* __restrict__ A2, int lda2,
    const unsigned short* __restrict__ B, const unsigned short* __restrict__ B2,
    long sBb, int ldb,
    void* __restrict__ Cptr, long sCb, int ldc,
    int K)
{
  constexpr int TK = 64;
  constexpr int WM = TM / 2, WN = TN / 2;
  constexpr int AM = WM / 16, AN = WN / 16;
  constexpr int ACH = TM / 8;
  constexpr int BCH = TN / 8;
  constexpr int NBLK = GX * GY;

  __shared__ unsigned short As[2][TM * TK];
  __shared__ unsigned short Bs[2][TN * TK];

  const int bid  = blockIdx.x;
  const int xcd  = bid & 7;
  const int slot = bid >> 3;
  const int bz   = xcd + 8 * (slot / NBLK);
  const int tix  = slot % NBLK;
  const int m0   = (tix % GX) * TM;
  const int n0   = (tix / GX) * TN;

  const unsigned short* Ab = A + (long)bz * sAb;
  const unsigned short* Bb = B + (long)bz * sBb;

  const int tid  = threadIdx.x;
  const int lane = tid & 63;
  const int wave = tid >> 6;
  const int wm = (wave >> 1) * WM;
  const int wn = (wave & 1) * WN;
  const int fr = lane & 15;
  const int fg = lane >> 4;
  const int fx = fr & 7;

  const int srow = lane >> 3;
  const int scol = (((lane & 7) ^ (lane >> 3)) & 7) * 8;  // pre-swizzled src col

  f32x4 acc[AM][AN];
#pragma unroll
  for (int i = 0; i < AM; i++)
#pragma unroll
    for (int j = 0; j < AN; j++) acc[i][j] = (f32x4)(0.f);

  auto stage = [&](int buf, int t) {
    const int k0 = t * TK;
    const unsigned short* asrc;
    int asl;
    if (KSW >= 0 && t >= KSW) { asrc = A2 + (k0 - KSW * TK); asl = lda2; }
    else                      { asrc = Ab + k0;              asl = lda;  }
#pragma unroll
    for (int i = 0; i < ACH / 4; i++) {
      const int c = wave * (ACH / 4) + i;
      __builtin_amdgcn_global_load_lds(
          (const __attribute__((address_space(1))) unsigned*)
              (asrc + (long)(m0 + c * 8 + srow) * asl + scol),
          (__attribute__((address_space(3))) unsigned*)(&As[buf][c * 512]),
          16, 0, 0);
    }
#pragma unroll
    for (int i = 0; i < BCH / 4; i++) {
      const int c = wave * (BCH / 4) + i;
      const int br = n0 + c * 8;      // chunk rows [br, br+8): one side of 512
      const unsigned short* bsrc = (BSW && br >= 512)
          ? B2 + (long)(br - 512) * ldb
          : Bb + (long)br * ldb;
      __builtin_amdgcn_global_load_lds(
          (const __attribute__((address_space(1))) unsigned*)
              (bsrc + (long)srow * ldb + k0 + scol),
          (__attribute__((address_space(3))) unsigned*)(&Bs[buf][c * 512]),
          16, 0, 0);
    }
  };

  const int NT = K / TK;
  stage(0, 0);
  __syncthreads();

  for (int t = 0; t < NT; ++t) {
    const int cur = t & 1;
    if (t + 1 < NT) stage(cur ^ 1, t + 1);

    const unsigned short* Ac = &As[cur][0];
    const unsigned short* Bc = &Bs[cur][0];
#pragma unroll
    for (int ks = 0; ks < 2; ks++) {
      s16x8 av[AM], bv[AN];
#pragma unroll
      for (int mt = 0; mt < AM; mt++)
        av[mt] = *(const s16x8*)
            &Ac[(wm + mt * 16 + fr) * TK + (((ks * 4 + fg) ^ fx) * 8)];
#pragma unroll
      for (int nt = 0; nt < AN; nt++)
        bv[nt] = *(const s16x8*)
            &Bc[(wn + nt * 16 + fr) * TK + (((ks * 4 + fg) ^ fx) * 8)];
#pragma unroll
      for (int mt = 0; mt < AM; mt++)
#pragma unroll
        for (int nt = 0; nt < AN; nt++)
          acc[mt][nt] = __builtin_amdgcn_mfma_f32_16x16x32_bf16(
              av[mt], bv[nt], acc[mt][nt], 0, 0, 0);
    }
    __syncthreads();
  }

  // D layout (verified m89): col = lane&15, row = (lane>>4)*4 + j
  if (OUT_F32) {
    float* C = (float*)Cptr + (long)bz * sCb;
#pragma unroll
    for (int mt = 0; mt < AM; mt++) {
      const int row = m0 + wm + mt * 16 + fg * 4;
#pragma unroll
      for (int nt = 0; nt < AN; nt++) {
        const int col = n0 + wn + nt * 16 + fr;
#pragma unroll
        for (int j = 0; j < 4; j++)
          C[(long)(row + j) * ldc + col] = acc[mt][nt][j];
      }
    }
  } else {
    unsigned short* C = (unsigned short*)Cptr + (long)bz * sCb;
#pragma unroll
    for (int mt = 0; mt < AM; mt++) {
      const int row = m0 + wm + mt * 16 + fg * 4;
#pragma unroll
      for (int nt = 0; nt < AN; nt++) {
        const int col = n0 + wn + nt * 16 + fr;
#pragma unroll
        for (int j = 0; j < 4; j++)
          C[(long)(row + j) * ldc + col] = f2bf(acc[mt][nt][j]);
      }
    }
  }
}

// ---------------------------------------------------------------------------
// convert_fused (+Wb): round-12 LDS scheme (scalar transposed writes,
// vectorized b128 reads).
// z<16, y<8:  x 64x64 tile -> Xb (bf16 straight) + XT (transposed, per-batch).
// z==0, y==8: e 64x64 tile -> eb (straight) + eT (transposed) ONCE.
// z>0,  y==8: early exit (e-block is batch-shared).
// z in {16,17}: Wb[m][k] = quadrant transpose of W0..W3, relu(striu) on W0.
// ---------------------------------------------------------------------------
__global__ __launch_bounds__(256) void convert_fused(
    const float* __restrict__ x, const float* __restrict__ e,
    const float* __restrict__ W0, const float* __restrict__ W1,
    const float* __restrict__ W2, const float* __restrict__ W3,
    unsigned short* __restrict__ XT, unsigned short* __restrict__ eT,
    unsigned short* __restrict__ Xb, unsigned short* __restrict__ eb,
    unsigned short* __restrict__ Wb)
{
  constexpr int KP = 66;             // k stride in elems (64 + 2 pad)
  __shared__ unsigned short t[64 * KP];   // [f][k], 8448B; Wb path reuses 4224B

  if (blockIdx.z >= 16) {
    const int tidx = (blockIdx.z - 16) * 288 + blockIdx.y * 32 + blockIdx.x;
    if (tidx >= 324) return;
    float* tw = (float*)t;                  // [32][33]
    const int m0 = (tidx / 18) * 32;
    const int k0 = (tidx % 18) * 32;
    const int r  = threadIdx.x >> 3;        // 0..31
    const int c4 = (threadIdx.x & 7) * 4;   // 0..28

    const int k = k0 + r;
    float4 v;
    if (m0 < 512) {
      if (k0 < 512) v = *(const float4*)&W0[k * 512 + m0 + c4];
      else          v = *(const float4*)&W1[(k - 512) * 512 + m0 + c4];
    } else {
      if (k0 < 512) v = *(const float4*)&W2[k * 64 + (m0 - 512) + c4];
      else          v = *(const float4*)&W3[(k - 512) * 64 + (m0 - 512) + c4];
    }
    tw[r * 33 + c4 + 0] = v.x; tw[r * 33 + c4 + 1] = v.y;
    tw[r * 33 + c4 + 2] = v.z; tw[r * 33 + c4 + 3] = v.w;
    __syncthreads();

    const int m = m0 + r;
    const bool tri = (m0 < 512) && (k0 < 512);
    s16x4 o;
#pragma unroll
    for (int j = 0; j < 4; ++j) {
      const int kk = k0 + c4 + j;
      float val = tw[(c4 + j) * 33 + r];
      if (tri) val = (m > kk) ? fmaxf(val, 0.f) : 0.f;
      o[j] = f2bf(val);
    }
    *(s16x4*)&Wb[m * 576 + k0 + c4] = o;
    return;
  }

  const int b  = blockIdx.z;
  const int k0 = blockIdx.x * 64;
  const bool isE = (blockIdx.y == 8);
  if (isE && b != 0) return;              // e-block is batch-shared
  const int f0 = blockIdx.y * 64;
  const int l  = threadIdx.x & 63;
  const int w  = threadIdx.x >> 6;
  const int fi = (l & 15) * 4;

#pragma unroll
  for (int it = 0; it < 4; ++it) {
    const int row = w * 16 + it * 4 + (l >> 4);   // k within tile
    const int k = k0 + row;
    float4 v = isE ? *(const float4*)&e[(long)k * 64 + fi]
                   : *(const float4*)&x[((long)b * 2048 + k) * 512 + f0 + fi];
    s16x4 o; o[0] = f2bf(v.x); o[1] = f2bf(v.y); o[2] = f2bf(v.z); o[3] = f2bf(v.w);
    if (isE) *(s16x4*)&eb[(long)k * 64 + fi] = o;
    else     *(s16x4*)&Xb[((long)b * 2048 + k) * 512 + f0 + fi] = o;
    t[(fi + 0) * KP + row] = o[0];
    t[(fi + 1) * KP + row] = o[1];
    t[(fi + 2) * KP + row] = o[2];
    t[(fi + 3) * KP + row] = o[3];
  }
  __syncthreads();

  const int fr = threadIdx.x >> 2;        // 0..63
  const int kq = (threadIdx.x & 3) * 8;   // 0,8,16,24
  const s16x8 o0 = *(const s16x8*)&t[fr * KP + kq];
  const s16x8 o1 = *(const s16x8*)&t[fr * KP + kq + 32];
  const long obase = isE ? ((long)fr * 2048 + k0)
                         : (((long)b * 512 + f0 + fr) * 2048 + k0);
  unsigned short* dst = isE ? eT : XT;
  *(s16x8*)&dst[obase + kq]      = o0;
  *(s16x8*)&dst[obase + kq + 32] = o1;
}

// ---------------------------------------------------------------------------
extern "C" void kernel_launch(void* const* d_in, const int* in_sizes, int n_in,
                              void* d_out, int out_size, void* d_ws, size_t ws_size,
                              hipStream_t stream) {
  const float* x  = (const float*)d_in[0];
  const float* e  = (const float*)d_in[1];
  const float* W0 = (const float*)d_in[2];
  const float* W1 = (const float*)d_in[3];
  const float* W2 = (const float*)d_in[4];
  const float* W3 = (const float*)d_in[5];
  float* out = (float*)d_out;

  const size_t SZ_XT  = (size_t)16 * 512 * 2048 * 2;  // 33,554,432
  const size_t SZ_ET  = (size_t)64 * 2048 * 2;        //    262,144
  const size_t SZ_CT  = (size_t)16 * 512 * 576 * 2;   //  9,437,184
  const size_t SZ_DT  = SZ_CT;
  const size_t SZ_WB  = (size_t)576 * 576 * 2;        //    663,552
  const size_t SZ_XB  = (size_t)16 * 2048 * 512 * 2;  // 33,554,432
  const size_t SZ_EB  = (size_t)2048 * 64 * 2;        //    262,144

  char* p = (char*)d_ws;
  unsigned short* XT = (unsigned short*)p;  p += SZ_XT;
  unsigned short* eT = (unsigned short*)p;  p += SZ_ET;
  unsigned short* CT = (unsigned short*)p;  p += SZ_CT;
  unsigned short* DT = (unsigned short*)p;  p += SZ_DT;
  unsigned short* Wb = (unsigned short*)p;  p += SZ_WB;
  unsigned short* Xb = (unsigned short*)p;  p += SZ_XB;
  unsigned short* eb = (unsigned short*)p;  p += SZ_EB;
  const size_t base = SZ_XT + SZ_ET + SZ_CT + SZ_DT + SZ_WB + SZ_XB + SZ_EB;
  if (ws_size < base) return;  // d_ws is 256MiB; loud failure otherwise

  // One fused pre-pass: x -> Xb+XT, e -> eb+eT (once), W0..W3 -> Wb
  convert_fused<<<dim3(32, 9, 18), 256, 0, stream>>>(
      x, e, W0, W1, W2, W3, XT, eT, Xb, eb, Wb);

  // Stage 1: CT[i][j] = sum_k XT[i][k] * {XT|eT}[j][k]  (M=512,N=576,K=2048)
  gemm_nt<64, 96, 8, 6, 0, -1, 1><<<768, 256, 0, stream>>>(
      XT, (long)512 * 2048, 2048, nullptr, 0,
      XT, eT, (long)512 * 2048, 2048,
      CT, (long)512 * 576, 576, 2048);

  // Stage 2: DT[t][m] = sum_f CT[t][f]*Wb[m][f]     (M=512, N=576, K=576)
  gemm_nt<64, 96, 8, 6, 0, -1, 0><<<768, 256, 0, stream>>>(
      CT, (long)512 * 576, 576, nullptr, 0,
      Wb, nullptr, 0L, 576,
      DT, (long)512 * 576, 576, 576);

  // Stage 3: out[n][t] = sum_m A[n][m]*DT[t][m]     (M=2048, N=512, K=576)
  // A: k-tiles 0..7 from Xb (per-batch), k-tile 8 from batch-shared eb.
  gemm_nt<128, 128, 16, 4, 1, 8, 0><<<1024, 256, 0, stream>>>(
      Xb, (long)2048 * 512, 512, eb, 64,
      DT, nullptr, (long)512 * 576, 576,
      out, (long)2048 * 512, 512, 576);
}